// Round 1
// baseline (349.253 us; speedup 1.0000x reference)
//
#include <hip/hip_runtime.h>

#define EPS 1e-10f
#define FAR_DELTA 1e10f

// One 64-lane wave per ray. P=128 samples: lane holds samples {lane, lane+64}.
// All global loads are contiguous/coalesced across the wave.
__global__ __launch_bounds__(256) void volrend_kernel(
    const float* __restrict__ density,   // [N,128]
    const float* __restrict__ feature,   // [N,128,3]
    const float* __restrict__ depth,     // [N,128]
    float* __restrict__ feat_out,        // [N,3]
    float* __restrict__ depth_out,       // [N]
    int N)
{
    const int lane = threadIdx.x & 63;
    const int wave = threadIdx.x >> 6;
    const int ray  = blockIdx.x * 4 + wave;
    if (ray >= N) return;

    const int P = 128;
    const float* dptr = density + (size_t)ray * P;
    const float* zptr = depth   + (size_t)ray * P;
    const float* fptr = feature + (size_t)ray * P * 3;

    // Coalesced loads: lanes cover [0,64) and [64,128) contiguously.
    float den0 = dptr[lane];
    float den1 = dptr[lane + 64];
    float z0   = zptr[lane];
    float z1   = zptr[lane + 64];

    // deltas: depth[i+1]-depth[i]; last sample gets FAR_DELTA.
    float zn0 = __shfl_down(z0, 1, 64);          // depth[lane+1] for lane<63
    float z64 = __shfl(z1, 0, 64);               // depth[64]
    if (lane == 63) zn0 = z64;                   // element 63 needs depth[64]
    float zn1 = __shfl_down(z1, 1, 64);          // depth[lane+65] for lane<63

    float delta0 = zn0 - z0;
    float delta1 = (lane == 63) ? FAR_DELTA : (zn1 - z1);

    // t = 1 - alpha = exp(-relu(density)*delta);  trans-term = t + EPS
    float t0 = expf(-fmaxf(den0, 0.0f) * delta0);
    float t1 = expf(-fmaxf(den1, 0.0f) * delta1);
    float alpha0 = 1.0f - t0;
    float alpha1 = 1.0f - t1;
    t0 += EPS;
    t1 += EPS;

    // Inclusive product scan of first half across lanes (Hillis-Steele).
    float p0 = t0;
    #pragma unroll
    for (int off = 1; off < 64; off <<= 1) {
        float v = __shfl_up(p0, off, 64);
        if (lane >= off) p0 *= v;
    }
    float T0 = __shfl(p0, 63, 64);               // product of elements 0..63

    // Exclusive transmittance for first half.
    float trans0 = __shfl_up(p0, 1, 64);
    if (lane == 0) trans0 = 1.0f;

    // Second half scan.
    float p1 = t1;
    #pragma unroll
    for (int off = 1; off < 64; off <<= 1) {
        float v = __shfl_up(p1, off, 64);
        if (lane >= off) p1 *= v;
    }
    float trans1 = __shfl_up(p1, 1, 64);
    if (lane == 0) trans1 = 1.0f;
    trans1 *= T0;

    float w0 = alpha0 * trans0;
    float w1 = alpha1 * trans1;

    // Feature loads: wave covers the contiguous 384-float row.
    float f00 = fptr[lane * 3 + 0];
    float f01 = fptr[lane * 3 + 1];
    float f02 = fptr[lane * 3 + 2];
    float f10 = fptr[(lane + 64) * 3 + 0];
    float f11 = fptr[(lane + 64) * 3 + 1];
    float f12 = fptr[(lane + 64) * 3 + 2];

    float acc0 = w0 * f00 + w1 * f10;
    float acc1 = w0 * f01 + w1 * f11;
    float acc2 = w0 * f02 + w1 * f12;
    float accd = w0 * z0  + w1 * z1;

    // Wave-wide butterfly sum (64 lanes).
    #pragma unroll
    for (int off = 32; off >= 1; off >>= 1) {
        acc0 += __shfl_xor(acc0, off, 64);
        acc1 += __shfl_xor(acc1, off, 64);
        acc2 += __shfl_xor(acc2, off, 64);
        accd += __shfl_xor(accd, off, 64);
    }

    if (lane == 0) {
        feat_out[ray * 3 + 0] = acc0;
        feat_out[ray * 3 + 1] = acc1;
        feat_out[ray * 3 + 2] = acc2;
        depth_out[ray]        = accd;
    }
}

extern "C" void kernel_launch(void* const* d_in, const int* in_sizes, int n_in,
                              void* d_out, int out_size, void* d_ws, size_t ws_size,
                              hipStream_t stream) {
    const float* density = (const float*)d_in[0];   // [N,128]
    const float* feature = (const float*)d_in[1];   // [N,128,3]
    const float* depth   = (const float*)d_in[2];   // [N,128]

    const int P = 128;
    const int N = in_sizes[0] / P;                  // 131072

    float* feat_out  = (float*)d_out;               // [N,3]
    float* depth_out = (float*)d_out + (size_t)N * 3; // [N]

    // 4 waves per block, one ray per wave.
    const int raysPerBlock = 4;
    dim3 grid((N + raysPerBlock - 1) / raysPerBlock);
    dim3 block(256);
    volrend_kernel<<<grid, block, 0, stream>>>(density, feature, depth,
                                               feat_out, depth_out, N);
}

// Round 2
// 349.215 us; speedup vs baseline: 1.0001x; 1.0001x over previous
//
#include <hip/hip_runtime.h>

#define EPS 1e-10f
#define FAR_DELTA 1e10f

// One ray per 16-lane group (4 rays per wave). Each lane holds 8 consecutive
// samples, loaded as float4 pairs -> fully coalesced dwordx4 traffic.
// Cross-lane work: 1 wave shfl_down (delta seam) + 4-step width-16 scan +
// 4-step width-16 butterfly. Everything else is lane-local serial FMA.
__global__ __launch_bounds__(256) void volrend_kernel(
    const float* __restrict__ density,   // [N,128]
    const float* __restrict__ feature,   // [N,128,3]
    const float* __restrict__ depth,     // [N,128]
    float* __restrict__ feat_out,        // [N,3]
    float* __restrict__ depth_out,       // [N]
    int N)
{
    const int tid  = threadIdx.x;
    const int lane = tid & 63;
    const int wv   = tid >> 6;        // wave within block (0..3)
    const int j    = lane & 15;       // sublane within ray group
    const int sub  = lane >> 4;       // ray slot within wave (0..3)
    const int ray  = blockIdx.x * 16 + wv * 4 + sub;
    if (ray >= N) return;

    // Per-lane bases: 8 samples starting at j*8. All 16B-aligned.
    const float4* d4 = (const float4*)(density + (size_t)ray * 128 + j * 8);
    const float4* z4 = (const float4*)(depth   + (size_t)ray * 128 + j * 8);
    const float4* f4 = (const float4*)(feature + (size_t)ray * 384 + j * 24);

    float4 dA = d4[0], dB = d4[1];
    float4 zA = z4[0], zB = z4[1];

    float z[8]  = {zA.x, zA.y, zA.z, zA.w, zB.x, zB.y, zB.z, zB.w};
    float dn[8] = {dA.x, dA.y, dA.z, dA.w, dB.x, dB.y, dB.z, dB.w};

    // Next lane's first depth (for the seam delta). j==15 overrides with FAR.
    float znext = __shfl_down(z[0], 1, 64);

    float al[8], tt[8];
    #pragma unroll
    for (int k = 0; k < 8; ++k) {
        float delta = (k < 7) ? (z[k + 1] - z[k])
                              : ((j == 15) ? FAR_DELTA : (znext - z[7]));
        float ex = __expf(-fmaxf(dn[k], 0.0f) * delta); // = 1 - alpha
        al[k] = 1.0f - ex;          // alpha
        tt[k] = ex + EPS;           // cumprod term (1 - alpha + eps)
    }

    // Lane-local inclusive product of the 8 terms.
    float loc = tt[0];
    #pragma unroll
    for (int k = 1; k < 8; ++k) loc *= tt[k];

    // Width-16 inclusive scan of lane totals, then exclusive shift.
    float s = loc;
    #pragma unroll
    for (int off = 1; off < 16; off <<= 1) {
        float v = __shfl_up(s, off, 16);
        if (j >= off) s *= v;
    }
    float excl = __shfl_up(s, 1, 16);
    if (j == 0) excl = 1.0f;

    // Feature loads (6 float4 = 24 floats = 8 samples x 3 channels).
    float4 F0 = f4[0], F1 = f4[1], F2 = f4[2], F3 = f4[3], F4 = f4[4], F5 = f4[5];
    float f[24] = {F0.x, F0.y, F0.z, F0.w, F1.x, F1.y, F1.z, F1.w,
                   F2.x, F2.y, F2.z, F2.w, F3.x, F3.y, F3.z, F3.w,
                   F4.x, F4.y, F4.z, F4.w, F5.x, F5.y, F5.z, F5.w};

    // Serial weights + accumulate (lane-local, good ILP).
    float trans = excl;
    float a0 = 0.0f, a1 = 0.0f, a2 = 0.0f, ad = 0.0f;
    #pragma unroll
    for (int k = 0; k < 8; ++k) {
        float wk = al[k] * trans;
        trans *= tt[k];
        a0 += wk * f[3 * k + 0];
        a1 += wk * f[3 * k + 1];
        a2 += wk * f[3 * k + 2];
        ad += wk * z[k];
    }

    // Width-16 butterfly reduction (4 independent chains).
    #pragma unroll
    for (int off = 8; off >= 1; off >>= 1) {
        a0 += __shfl_xor(a0, off, 16);
        a1 += __shfl_xor(a1, off, 16);
        a2 += __shfl_xor(a2, off, 16);
        ad += __shfl_xor(ad, off, 16);
    }

    if (j == 0) {
        feat_out[(size_t)ray * 3 + 0] = a0;
        feat_out[(size_t)ray * 3 + 1] = a1;
        feat_out[(size_t)ray * 3 + 2] = a2;
        depth_out[ray] = ad;
    }
}

extern "C" void kernel_launch(void* const* d_in, const int* in_sizes, int n_in,
                              void* d_out, int out_size, void* d_ws, size_t ws_size,
                              hipStream_t stream) {
    const float* density = (const float*)d_in[0];   // [N,128]
    const float* feature = (const float*)d_in[1];   // [N,128,3]
    const float* depth   = (const float*)d_in[2];   // [N,128]

    const int P = 128;
    const int N = in_sizes[0] / P;                  // 131072

    float* feat_out  = (float*)d_out;                 // [N,3]
    float* depth_out = (float*)d_out + (size_t)N * 3; // [N]

    // 16 rays per block (4 waves x 4 rays).
    dim3 grid((N + 15) / 16);
    dim3 block(256);
    volrend_kernel<<<grid, block, 0, stream>>>(density, feature, depth,
                                               feat_out, depth_out, N);
}